// Round 1
// baseline (29735.635 us; speedup 1.0000x reference)
//
#include <hip/hip_runtime.h>
#include <hip/hip_bf16.h>

#define BB 64
#define TT_ 512
#define IN_ 256
#define HH 1024
#define G4 4096
#define OO 256

__device__ __forceinline__ float sigmoidf_(float v) {
    return 1.f / (1.f + __expf(-v));
}
__device__ __forceinline__ float tanhf_(float v) {
    float vc = fminf(fmaxf(v, -15.f), 15.f);
    float e = __expf(2.f * vc);
    return (e - 1.f) / (e + 1.f);
}

// ---------------- encoder step ----------------
// grid 256, block 512. WG: 4 H-dims (16 gate rows) x all 64 batches.
// K = 1280 (h:1024 + x:256), staged in 20 chunks of 64 into LDS.
// Thread (b, ks): ks in 0..7 owns k-sub [ks*8, ks*8+8) of every chunk,
// accumulates 16 rows; partials reduced across ks in LDS, gates fused.
__global__ __launch_bounds__(512)
void enc_step(const float* __restrict__ x,
              const float* __restrict__ Wih, const float* __restrict__ Whh,
              const float* __restrict__ bih, const float* __restrict__ bhh,
              const float* __restrict__ hinT, float* __restrict__ houtT,
              float* __restrict__ cT, int t)
{
    __shared__ float hx[64][68];     // [k within chunk][b], pad 68 for b128 align
    __shared__ float pp[8][16][64];  // [ks][row][b] partial sums
    const int tid = threadIdx.x;
    const int b   = tid & 63;
    const int ks  = tid >> 6;        // 0..7
    const int d0  = blockIdx.x * 4;

    float acc[16];
#pragma unroll
    for (int r = 0; r < 16; ++r) acc[r] = 0.f;

    for (int kc = 0; kc < 20; ++kc) {
        const int k0 = kc * 64;
        __syncthreads();
        // ---- stage 64 k x 64 b chunk into hx[k][b] ----
        if (kc < 16) {
            // h^T chunk: hinT is [1024][64], linear in (k*64+b) -> coalesced f4
#pragma unroll
            for (int u = 0; u < 2; ++u) {
                int f = u * 512 + tid;                 // float4 index 0..1023
                float4 v = *(const float4*)(hinT + (size_t)k0 * 64 + (size_t)f * 4);
                int kk = f >> 4;          // (f*4)>>6
                int bb = (f * 4) & 63;
                *(float4*)&hx[kk][bb] = v;
            }
        } else {
            // x chunk: x[b][t][i], coalesced over i
            int i0 = k0 - 1024;
#pragma unroll
            for (int u = 0; u < 2; ++u) {
                int f = u * 512 + tid;                 // 0..1023
                int b2 = f >> 4, is4 = (f & 15) * 4;
                float4 v = *(const float4*)(x + (size_t)b2 * (TT_ * IN_) +
                                            (size_t)t * IN_ + i0 + is4);
                hx[is4 + 0][b2] = v.x;
                hx[is4 + 1][b2] = v.y;
                hx[is4 + 2][b2] = v.z;
                hx[is4 + 3][b2] = v.w;
            }
        }
        __syncthreads();

        // ---- compute: this thread's k-sub ----
        const int kb = ks * 8;
        float hv[8];
#pragma unroll
        for (int kk = 0; kk < 8; ++kk) hv[kk] = hx[kb + kk][b];

        if (kc < 16) {
#pragma unroll
            for (int r = 0; r < 16; ++r) {
                int q = r >> 2, dd = r & 3;
                const float* wr = Whh + ((size_t)(q * HH + d0 + dd)) * HH + k0 + kb;
                float4 w0 = *(const float4*)(wr);
                float4 w1 = *(const float4*)(wr + 4);
                acc[r] += hv[0] * w0.x + hv[1] * w0.y + hv[2] * w0.z + hv[3] * w0.w
                        + hv[4] * w1.x + hv[5] * w1.y + hv[6] * w1.z + hv[7] * w1.w;
            }
        } else {
            int i0 = k0 - 1024;
#pragma unroll
            for (int r = 0; r < 16; ++r) {
                int q = r >> 2, dd = r & 3;
                const float* wr = Wih + ((size_t)(q * HH + d0 + dd)) * IN_ + i0 + kb;
                float4 w0 = *(const float4*)(wr);
                float4 w1 = *(const float4*)(wr + 4);
                acc[r] += hv[0] * w0.x + hv[1] * w0.y + hv[2] * w0.z + hv[3] * w0.w
                        + hv[4] * w1.x + hv[5] * w1.y + hv[6] * w1.z + hv[7] * w1.w;
            }
        }
    }

    // ---- reduce partials across ks, fuse gates ----
#pragma unroll
    for (int r = 0; r < 16; ++r) pp[ks][r][b] = acc[r];
    __syncthreads();

    if (tid < 256) {
        int dd = tid >> 6, bb = tid & 63;
        float pre[4];
#pragma unroll
        for (int q = 0; q < 4; ++q) {
            int r = q * 4 + dd;
            float s = 0.f;
#pragma unroll
            for (int k = 0; k < 8; ++k) s += pp[k][r][bb];
            int j = q * HH + d0 + dd;
            pre[q] = s + bih[j] + bhh[j];
        }
        float ig = sigmoidf_(pre[0]);
        float fg = sigmoidf_(pre[1]);
        float gg = tanhf_(pre[2]);
        float og = sigmoidf_(pre[3]);
        int d = d0 + dd;
        float c_old = cT[d * 64 + bb];
        float c_new = fg * c_old + ig * gg;
        cT[d * 64 + bb]    = c_new;
        houtT[d * 64 + bb] = og * tanhf_(c_new);
    }
}

// ---------------- hdec = h_final @ dec_Whh^T + dec_bih + dec_bhh ----------------
// grid 256 (64 b x 4 j-chunks), block 256
__global__ __launch_bounds__(256)
void hdec_kernel(const float* __restrict__ hT, const float* __restrict__ Whh,
                 const float* __restrict__ bih, const float* __restrict__ bhh,
                 float* __restrict__ hdec)
{
    __shared__ float hb[1024];
    const int tid = threadIdx.x;
    const int b  = blockIdx.x >> 2;
    const int j0 = (blockIdx.x & 3) * 1024;
#pragma unroll
    for (int u = 0; u < 4; ++u) {
        int k = u * 256 + tid;
        hb[k] = hT[k * 64 + b];
    }
    __syncthreads();
#pragma unroll
    for (int rr = 0; rr < 4; ++rr) {
        int j = j0 + rr * 256 + tid;
        const float* wr = Whh + (size_t)j * HH;
        float a = bih[j] + bhh[j];
        for (int k = 0; k < 1024; k += 4) {
            float4 wv = *(const float4*)(wr + k);
            float4 hv = *(const float4*)&hb[k];
            a += hv.x * wv.x + hv.y * wv.y + hv.z * wv.z + hv.w * wv.w;
        }
        hdec[(size_t)b * G4 + j] = a;
    }
}

// ---------------- fused decoder: pre -> gates -> h_new -> FC ----------------
// grid 2048 (b x 32 t-tiles of 16), block 256
__global__ __launch_bounds__(256)
void dec_fused(const float* __restrict__ x, const float* __restrict__ Wih,
               const float* __restrict__ hdec, const float* __restrict__ cT,
               const float* __restrict__ fcW, const float* __restrict__ fcb,
               float* __restrict__ out)
{
    __shared__ __align__(16) float xs[16][256];              // 16 KB
    __shared__ __align__(16) __hip_bfloat16 ps[4][16][512];  // 64 KB
    const int tid = threadIdx.x;
    const int w  = blockIdx.x;
    const int b  = w >> 5;
    const int t0 = (w & 31) * 16;

    // stage x tile [16 t][256 i]
#pragma unroll
    for (int u = 0; u < 16; ++u) {
        int e = u * 256 + tid;
        int tt = e >> 8, k = e & 255;
        xs[tt][k] = x[(size_t)b * (TT_ * IN_) + (size_t)(t0 + tt) * IN_ + k];
    }

    float facc[16];
#pragma unroll
    for (int tt = 0; tt < 16; ++tt) facc[tt] = fcb[tid];

    for (int dc = 0; dc < 2; ++dc) {
        __syncthreads();  // xs ready (dc=0) / prev FC done with ps overlay (dc=1)
        // ---- P1: pre for 512 dims x 4 gates, rows {tid, tid+256} ----
        for (int q = 0; q < 4; ++q) {
            int ja = q * HH + dc * 512 + tid;
            int jb = ja + 256;
            float ha = hdec[(size_t)b * G4 + ja];
            float hb2 = hdec[(size_t)b * G4 + jb];
            float aa[16], ab[16];
#pragma unroll
            for (int tt = 0; tt < 16; ++tt) { aa[tt] = ha; ab[tt] = hb2; }
            const float* wa = Wih + (size_t)ja * IN_;
            const float* wb = Wih + (size_t)jb * IN_;
            for (int k = 0; k < 256; k += 4) {
                float4 va = *(const float4*)(wa + k);
                float4 vb = *(const float4*)(wb + k);
#pragma unroll
                for (int tt = 0; tt < 16; ++tt) {
                    float4 xv = *(const float4*)&xs[tt][k];
                    aa[tt] += xv.x * va.x + xv.y * va.y + xv.z * va.z + xv.w * va.w;
                    ab[tt] += xv.x * vb.x + xv.y * vb.y + xv.z * vb.z + xv.w * vb.w;
                }
            }
#pragma unroll
            for (int tt = 0; tt < 16; ++tt) {
                ps[q][tt][tid]       = __float2bfloat16(aa[tt]);
                ps[q][tt][tid + 256] = __float2bfloat16(ab[tt]);
            }
        }
        __syncthreads();

        // ---- P2: gates -> h_new (to registers, then overlay ps as f32) ----
        float hn[32];
#pragma unroll
        for (int vv = 0; vv < 32; ++vv) {
            int p = vv * 256 + tid;
            int dl = p & 511, tt = p >> 9;
            float ig = __bfloat162float(ps[0][tt][dl]);
            float fg = __bfloat162float(ps[1][tt][dl]);
            float gg = __bfloat162float(ps[2][tt][dl]);
            float og = __bfloat162float(ps[3][tt][dl]);
            ig = sigmoidf_(ig); fg = sigmoidf_(fg);
            gg = tanhf_(gg);    og = sigmoidf_(og);
            float cv = cT[(dc * 512 + dl) * 64 + b];
            float cn = fg * cv + ig * gg;
            hn[vv] = og * tanhf_(cn);
        }
        __syncthreads();
        float* hnf = (float*)&ps[0][0][0];   // overlay: [16][512] f32 = 32 KB
#pragma unroll
        for (int vv = 0; vv < 32; ++vv) {
            int p = vv * 256 + tid;
            int dl = p & 511, tt = p >> 9;
            hnf[tt * 512 + dl] = hn[vv];
        }
        __syncthreads();

        // ---- P3: FC partial over this 512-dim chunk, o = tid ----
        const float* wo = fcW + (size_t)tid * HH + dc * 512;
        for (int k = 0; k < 512; k += 4) {
            float4 wv = *(const float4*)(wo + k);
#pragma unroll
            for (int tt = 0; tt < 16; ++tt) {
                float4 hv = *(const float4*)&hnf[tt * 512 + k];
                facc[tt] += hv.x * wv.x + hv.y * wv.y + hv.z * wv.z + hv.w * wv.w;
            }
        }
    }

#pragma unroll
    for (int tt = 0; tt < 16; ++tt) {
        out[(size_t)b * (TT_ * OO) + (size_t)(t0 + tt) * OO + tid] = facc[tt];
    }
}

extern "C" void kernel_launch(void* const* d_in, const int* in_sizes, int n_in,
                              void* d_out, int out_size, void* d_ws, size_t ws_size,
                              hipStream_t stream) {
    const float* x    = (const float*)d_in[0];
    const float* eWih = (const float*)d_in[1];
    const float* eWhh = (const float*)d_in[2];
    const float* ebih = (const float*)d_in[3];
    const float* ebhh = (const float*)d_in[4];
    const float* dWih = (const float*)d_in[5];
    const float* dWhh = (const float*)d_in[6];
    const float* dbih = (const float*)d_in[7];
    const float* dbhh = (const float*)d_in[8];
    const float* fcW  = (const float*)d_in[9];
    const float* fcb  = (const float*)d_in[10];

    // ws layout (f32): hT0[1024][64] | hT1[1024][64] | cT[1024][64] | hdec[64][4096]
    float* ws   = (float*)d_ws;
    float* hT0  = ws;
    float* hT1  = ws + 65536;
    float* cT   = ws + 2 * 65536;
    float* hdec = ws + 3 * 65536;   // total 1.75 MB

    hipMemsetAsync(hT0, 0, 65536 * sizeof(float), stream);
    hipMemsetAsync(cT,  0, 65536 * sizeof(float), stream);

    for (int t = 0; t < TT_; ++t) {
        const float* hin = (t & 1) ? hT1 : hT0;
        float* hout      = (t & 1) ? hT0 : hT1;
        enc_step<<<dim3(256), dim3(512), 0, stream>>>(x, eWih, eWhh, ebih, ebhh,
                                                      hin, hout, cT, t);
    }
    // after 512 steps final h is in hT0
    hdec_kernel<<<dim3(256), dim3(256), 0, stream>>>(hT0, dWhh, dbih, dbhh, hdec);
    dec_fused<<<dim3(2048), dim3(256), 0, stream>>>(x, dWih, hdec, cT, fcW, fcb,
                                                    (float*)d_out);
}

// Round 2
// 7703.008 us; speedup vs baseline: 3.8603x; 3.8603x over previous
//
#include <hip/hip_runtime.h>
#include <hip/hip_bf16.h>

#define BB 64
#define TT_ 512
#define IN_ 256
#define HH 1024
#define G4 4096
#define OO 256

typedef _Float16 half8 __attribute__((ext_vector_type(8)));
typedef float f32x4 __attribute__((ext_vector_type(4)));

__device__ __forceinline__ float sigmoidf_(float v) {
    return 1.f / (1.f + __expf(-v));
}
__device__ __forceinline__ float tanhf_(float v) {
    float vc = fminf(fmaxf(v, -15.f), 15.f);
    float e = __expf(2.f * vc);
    return (e - 1.f) / (e + 1.f);
}

// ---------------- weight pack: [Whh | Wih] -> fp16 A-fragment-major ----------------
// Apk[jt(256)][kc(40)][lane(64)][e(8)], jt = j>>4 (j natural 0..4095).
// A-frag (16x16x32): lane l holds A[m = l&15][k = (l>>4)*8 + e].
__global__ __launch_bounds__(256)
void pack_a(const float* __restrict__ Whh, const float* __restrict__ Wih,
            _Float16* __restrict__ Apk)
{
    int id = blockIdx.x * 256 + threadIdx.x;      // < 655360
    int jt = id / 2560;
    int rem = id - jt * 2560;
    int kc = rem >> 6, l = rem & 63;
    int j  = jt * 16 + (l & 15);
    int k0 = (l >> 4) << 3;
    half8 v;
    if (kc < 32) {
        const float* s = Whh + (size_t)j * HH + kc * 32 + k0;
#pragma unroll
        for (int e = 0; e < 8; ++e) v[e] = (_Float16)s[e];
    } else {
        const float* s = Wih + (size_t)j * IN_ + (kc - 32) * 32 + k0;
#pragma unroll
        for (int e = 0; e < 8; ++e) v[e] = (_Float16)s[e];
    }
    ((half8*)Apk)[id] = v;
}

// ---------------- x pack: fp16 B-fragment-major per t ----------------
// Xpk[t][kc2(8)][bt(4)][lane(64)][e(8)]; B-frag: lane l holds B[k=(l>>4)*8+e][n=l&15].
__global__ __launch_bounds__(256)
void pack_x(const float* __restrict__ x, _Float16* __restrict__ Xpk)
{
    int id = blockIdx.x * 256 + threadIdx.x;  // < 1048576
    int l = id & 63, bt = (id >> 6) & 3, kc2 = (id >> 8) & 7, t = id >> 11;
    int b  = bt * 16 + (l & 15);
    int i0 = kc2 * 32 + ((l >> 4) << 3);
    const float* s = x + ((size_t)b * TT_ + t) * IN_ + i0;
    half8 v;
#pragma unroll
    for (int e = 0; e < 8; ++e) v[e] = (_Float16)s[e];
    ((half8*)Xpk)[id] = v;
}

__global__ __launch_bounds__(256)
void pack_bias(const float* __restrict__ bih, const float* __restrict__ bhh,
               float* __restrict__ biasc)
{
    int j = blockIdx.x * 256 + threadIdx.x;
    if (j < G4) biasc[j] = bih[j] + bhh[j];
}

// ---------------- encoder step: MFMA GEMM + fused gates ----------------
// grid 256 (db = bid>>2 in [0,64), bq = bid&3), block 256 (4 waves).
// Wave g computes pre[gate g] for d-block db x 16 b (bq): D[16j][16b], K=1280.
__global__ __launch_bounds__(256)
void enc_step_mfma(const _Float16* __restrict__ Apk,
                   const _Float16* __restrict__ Xpk,
                   const _Float16* __restrict__ Hin,
                   _Float16* __restrict__ Hout,
                   const float* __restrict__ biasc,
                   float* __restrict__ cT,
                   float* __restrict__ hT,
                   int t, int last)
{
    __shared__ float preLDS[4][16][16];
    const int tid = threadIdx.x;
    const int g = tid >> 6, lane = tid & 63;
    const int db = blockIdx.x >> 2, bq = blockIdx.x & 3;
    const int jt = g * 64 + db;

    const half8* A8 = (const half8*)Apk + (size_t)jt * 40 * 64 + lane;
    const half8* H8 = (const half8*)Hin + (size_t)bq * 64 + lane;
    const half8* X8 = (const half8*)Xpk + (((size_t)t * 8) * 4 + bq) * 64 + lane;

    f32x4 acc = {0.f, 0.f, 0.f, 0.f};
#pragma unroll 4
    for (int kc = 0; kc < 32; ++kc) {
        half8 a = A8[kc * 64];
        half8 bfr = H8[kc * 256];
        acc = __builtin_amdgcn_mfma_f32_16x16x32_f16(a, bfr, acc, 0, 0, 0);
    }
#pragma unroll 4
    for (int kc2 = 0; kc2 < 8; ++kc2) {
        half8 a = A8[(32 + kc2) * 64];
        half8 bfr = X8[kc2 * 256];
        acc = __builtin_amdgcn_mfma_f32_16x16x32_f16(a, bfr, acc, 0, 0, 0);
    }
    // D layout: row = (lane>>4)*4 + reg, col = lane&15  [m89-verified]
#pragma unroll
    for (int r = 0; r < 4; ++r)
        preLDS[g][(lane >> 4) * 4 + r][lane & 15] = acc[r];
    __syncthreads();

    const int dl = tid >> 4, bl = tid & 15;
    const int d = db * 16 + dl, b = bq * 16 + bl;
    float pi = preLDS[0][dl][bl] + biasc[d];
    float pf = preLDS[1][dl][bl] + biasc[HH + d];
    float pg = preLDS[2][dl][bl] + biasc[2 * HH + d];
    float po = preLDS[3][dl][bl] + biasc[3 * HH + d];
    float ig = sigmoidf_(pi), fg = sigmoidf_(pf);
    float gg = tanhf_(pg),    og = sigmoidf_(po);
    float c_old = cT[d * 64 + b];
    float c_new = fg * c_old + ig * gg;
    cT[d * 64 + b] = c_new;
    float h = og * tanhf_(c_new);
    // write h into next step's B-frag layout: kc=d>>5, lg=(d>>3)&3, e=d&7, l=lg*16+bl
    Hout[((((size_t)(d >> 5) * 4 + bq) * 64) + ((d >> 3) & 3) * 16 + bl) * 8 + (d & 7)] =
        (_Float16)h;
    if (last) hT[d * 64 + b] = h;
}

// ---------------- hdec = h_final @ dec_Whh^T + dec_bih + dec_bhh ----------------
__global__ __launch_bounds__(256)
void hdec_kernel(const float* __restrict__ hT, const float* __restrict__ Whh,
                 const float* __restrict__ bih, const float* __restrict__ bhh,
                 float* __restrict__ hdec)
{
    __shared__ float hb[1024];
    const int tid = threadIdx.x;
    const int b  = blockIdx.x >> 2;
    const int j0 = (blockIdx.x & 3) * 1024;
#pragma unroll
    for (int u = 0; u < 4; ++u) {
        int k = u * 256 + tid;
        hb[k] = hT[k * 64 + b];
    }
    __syncthreads();
#pragma unroll
    for (int rr = 0; rr < 4; ++rr) {
        int j = j0 + rr * 256 + tid;
        const float* wr = Whh + (size_t)j * HH;
        float a = bih[j] + bhh[j];
        for (int k = 0; k < 1024; k += 4) {
            float4 wv = *(const float4*)(wr + k);
            float4 hv = *(const float4*)&hb[k];
            a += hv.x * wv.x + hv.y * wv.y + hv.z * wv.z + hv.w * wv.w;
        }
        hdec[(size_t)b * G4 + j] = a;
    }
}

// ---------------- fused decoder: pre -> gates -> h_new -> FC ----------------
__global__ __launch_bounds__(256)
void dec_fused(const float* __restrict__ x, const float* __restrict__ Wih,
               const float* __restrict__ hdec, const float* __restrict__ cT,
               const float* __restrict__ fcW, const float* __restrict__ fcb,
               float* __restrict__ out)
{
    __shared__ __align__(16) float xs[16][256];              // 16 KB
    __shared__ __align__(16) __hip_bfloat16 ps[4][16][512];  // 64 KB
    const int tid = threadIdx.x;
    const int w  = blockIdx.x;
    const int b  = w >> 5;
    const int t0 = (w & 31) * 16;

#pragma unroll
    for (int u = 0; u < 16; ++u) {
        int e = u * 256 + tid;
        int tt = e >> 8, k = e & 255;
        xs[tt][k] = x[(size_t)b * (TT_ * IN_) + (size_t)(t0 + tt) * IN_ + k];
    }

    float facc[16];
#pragma unroll
    for (int tt = 0; tt < 16; ++tt) facc[tt] = fcb[tid];

    for (int dc = 0; dc < 2; ++dc) {
        __syncthreads();
        for (int q = 0; q < 4; ++q) {
            int ja = q * HH + dc * 512 + tid;
            int jb = ja + 256;
            float ha = hdec[(size_t)b * G4 + ja];
            float hb2 = hdec[(size_t)b * G4 + jb];
            float aa[16], ab[16];
#pragma unroll
            for (int tt = 0; tt < 16; ++tt) { aa[tt] = ha; ab[tt] = hb2; }
            const float* wa = Wih + (size_t)ja * IN_;
            const float* wb = Wih + (size_t)jb * IN_;
            for (int k = 0; k < 256; k += 4) {
                float4 va = *(const float4*)(wa + k);
                float4 vb = *(const float4*)(wb + k);
#pragma unroll
                for (int tt = 0; tt < 16; ++tt) {
                    float4 xv = *(const float4*)&xs[tt][k];
                    aa[tt] += xv.x * va.x + xv.y * va.y + xv.z * va.z + xv.w * va.w;
                    ab[tt] += xv.x * vb.x + xv.y * vb.y + xv.z * vb.z + xv.w * vb.w;
                }
            }
#pragma unroll
            for (int tt = 0; tt < 16; ++tt) {
                ps[q][tt][tid]       = __float2bfloat16(aa[tt]);
                ps[q][tt][tid + 256] = __float2bfloat16(ab[tt]);
            }
        }
        __syncthreads();

        float hn[32];
#pragma unroll
        for (int vv = 0; vv < 32; ++vv) {
            int p = vv * 256 + tid;
            int dl = p & 511, tt = p >> 9;
            float ig = __bfloat162float(ps[0][tt][dl]);
            float fg = __bfloat162float(ps[1][tt][dl]);
            float gg = __bfloat162float(ps[2][tt][dl]);
            float og = __bfloat162float(ps[3][tt][dl]);
            ig = sigmoidf_(ig); fg = sigmoidf_(fg);
            gg = tanhf_(gg);    og = sigmoidf_(og);
            float cv = cT[(dc * 512 + dl) * 64 + b];
            float cn = fg * cv + ig * gg;
            hn[vv] = og * tanhf_(cn);
        }
        __syncthreads();
        float* hnf = (float*)&ps[0][0][0];
#pragma unroll
        for (int vv = 0; vv < 32; ++vv) {
            int p = vv * 256 + tid;
            int dl = p & 511, tt = p >> 9;
            hnf[tt * 512 + dl] = hn[vv];
        }
        __syncthreads();

        const float* wo = fcW + (size_t)tid * HH + dc * 512;
        for (int k = 0; k < 512; k += 4) {
            float4 wv = *(const float4*)(wo + k);
#pragma unroll
            for (int tt = 0; tt < 16; ++tt) {
                float4 hv = *(const float4*)&hnf[tt * 512 + k];
                facc[tt] += hv.x * wv.x + hv.y * wv.y + hv.z * wv.z + hv.w * wv.w;
            }
        }
    }

#pragma unroll
    for (int tt = 0; tt < 16; ++tt) {
        out[(size_t)b * (TT_ * OO) + (size_t)(t0 + tt) * OO + tid] = facc[tt];
    }
}

extern "C" void kernel_launch(void* const* d_in, const int* in_sizes, int n_in,
                              void* d_out, int out_size, void* d_ws, size_t ws_size,
                              hipStream_t stream) {
    const float* x    = (const float*)d_in[0];
    const float* eWih = (const float*)d_in[1];
    const float* eWhh = (const float*)d_in[2];
    const float* ebih = (const float*)d_in[3];
    const float* ebhh = (const float*)d_in[4];
    const float* dWih = (const float*)d_in[5];
    const float* dWhh = (const float*)d_in[6];
    const float* dbih = (const float*)d_in[7];
    const float* dbhh = (const float*)d_in[8];
    const float* fcW  = (const float*)d_in[9];
    const float* fcb  = (const float*)d_in[10];

    // ws layout (f32 words): hT 65536 | cT 65536 | hdec 262144 | biasc 4096 |
    // then fp16: Hf0 65536 | Hf1 65536 | Apk 5242880 | Xpk 8388608  (~28 MB total)
    float* ws    = (float*)d_ws;
    float* hT    = ws;
    float* cT    = ws + 65536;
    float* hdec  = ws + 131072;
    float* biasc = ws + 393216;
    _Float16* fp  = (_Float16*)(ws + 397312);
    _Float16* Hf0 = fp;
    _Float16* Hf1 = fp + 65536;
    _Float16* Apk = fp + 131072;
    _Float16* Xpk = Apk + 5242880;

    pack_a<<<dim3(2560), dim3(256), 0, stream>>>(eWhh, eWih, Apk);
    pack_x<<<dim3(4096), dim3(256), 0, stream>>>(x, Xpk);
    pack_bias<<<dim3(16), dim3(256), 0, stream>>>(ebih, ebhh, biasc);
    hipMemsetAsync(cT, 0, 65536 * sizeof(float), stream);
    hipMemsetAsync(Hf0, 0, 65536 * sizeof(_Float16), stream);

    for (int t = 0; t < TT_; ++t) {
        const _Float16* Hin = (t & 1) ? Hf1 : Hf0;
        _Float16* Hout      = (t & 1) ? Hf0 : Hf1;
        enc_step_mfma<<<dim3(256), dim3(256), 0, stream>>>(
            Apk, Xpk, Hin, Hout, biasc, cT, hT, t, (t == TT_ - 1) ? 1 : 0);
    }
    hdec_kernel<<<dim3(256), dim3(256), 0, stream>>>(hT, dWhh, dbih, dbhh, hdec);
    dec_fused<<<dim3(2048), dim3(256), 0, stream>>>(x, dWih, hdec, cT, fcW, fcb,
                                                    (float*)d_out);
}